// Round 5
// baseline (1783.332 us; speedup 1.0000x reference)
//
#include <hip/hip_runtime.h>
#include <cfloat>
#include <cmath>

#define NROWS 32768
#define DDIM  512
#define KCODES 2048

// output layout (floats): [loss][q_st N*512][perplexity][encodings N*K]
#define OUT_Q    1
#define OUT_PERP 16777217
#define OUT_ENC  16777218

// scratch offsets in float slots, relative to S = d_out + OUT_ENC + 2
// (capacity 67,108,862 float slots inside the encodings region)
#define H_OFF     0           // 16,777,216  h fp32 [32768][512]
#define AP_OFF    16777216    // 16,777,216  h split bf16 [32768][1024] (hi|lo)
#define BP_OFF    33554432    //  1,048,576  emb split bf16 [2048][1024]
#define XS_OFF    34603008    // 16,777,216  X split bf16 [32768][1024]
#define WS_OFF    51380224    //    262,144  W split bf16 [512][1024]
#define ENORM_OFF 51642368    //      2,048
#define PVAL_OFF  51644416    //  1,048,576 (32 x 32768)
#define PSEC_OFF  52692992    //  1,048,576
#define PIDX_OFF  53741568    //  1,048,576 -> end 54,790,144

#define RESCORE_EPS 0.006f

typedef __attribute__((ext_vector_type(8))) short  bf16x8;
typedef __attribute__((ext_vector_type(4))) float  f32x4;

__device__ __forceinline__ unsigned short f2bf(float f) {
  unsigned u = __float_as_uint(f);
  unsigned r = (u + 0x7FFF + ((u >> 16) & 1)) >> 16;
  return (unsigned short)r;
}
__device__ __forceinline__ float bf2f(unsigned short h) {
  return __uint_as_float(((unsigned)h) << 16);
}
__device__ __forceinline__ void gload16(const void* g, void* l) {
  __builtin_amdgcn_global_load_lds(
      (const __attribute__((address_space(1))) unsigned int*)g,
      (__attribute__((address_space(3))) unsigned int*)l, 16, 0, 0);
}
__device__ __forceinline__ ushort4 hi4(float4 v) {
  return make_ushort4(f2bf(v.x), f2bf(v.y), f2bf(v.z), f2bf(v.w));
}
__device__ __forceinline__ ushort4 lo4(float4 v, ushort4 h) {
  return make_ushort4(f2bf(v.x - bf2f(h.x)), f2bf(v.y - bf2f(h.y)),
                      f2bf(v.z - bf2f(h.z)), f2bf(v.w - bf2f(h.w)));
}

// fp32 [R][256] half -> hi/lo into Xs [R][1024] at column offset colOff
__global__ __launch_bounds__(256) void ksplit_half(const float* __restrict__ src,
    unsigned short* __restrict__ Xs, int colOff) {
  const int tid = blockIdx.x * 256 + threadIdx.x;   // 8192 blocks
  const int n  = tid >> 6;
  const int c4 = (tid & 63) * 4;
  const float4 v = *(const float4*)&src[(size_t)n * 256 + c4];
  const ushort4 h = hi4(v);
  unsigned short* row = Xs + (size_t)n * 1024;
  *(ushort4*)&row[colOff + c4]       = h;
  *(ushort4*)&row[512 + colOff + c4] = lo4(v, h);
}

// fp32 [R][512] -> hi/lo into dst [R][1024]
__global__ __launch_bounds__(256) void ksplit_full(const float* __restrict__ src,
    unsigned short* __restrict__ dst) {
  const int tid = blockIdx.x * 256 + threadIdx.x;
  const int r  = tid >> 7;
  const int c4 = (tid & 127) * 4;
  const float4 v = *(const float4*)&src[(size_t)r * 512 + c4];
  const ushort4 h = hi4(v);
  unsigned short* row = dst + (size_t)r * 1024;
  *(ushort4*)&row[c4]       = h;
  *(ushort4*)&row[512 + c4] = lo4(v, h);
}

__global__ __launch_bounds__(64) void kenorm(const float* __restrict__ emb,
                                             float* __restrict__ enorms) {
  const int k = blockIdx.x;
  const int t = threadIdx.x;
  float s = 0.f;
#pragma unroll
  for (int i = 0; i < 8; ++i) {
    const float v = emb[k * DDIM + t + i * 64];
    s = fmaf(v, v, s);
  }
#pragma unroll
  for (int off = 32; off > 0; off >>= 1) s += __shfl_down(s, off);
  if (t == 0) enorms[k] = s;
}

// h = X @ W^T + b via split-bf16 MFMA, 4-term (hi*hi, lo*hi, hi*lo, lo*lo):
// h is ref-grade fp32 (residual ~1e-7/comp). Writes h fp32 and Ap=split(h).
__global__ __launch_bounds__(256) void kgemm1_mfma(
    const unsigned short* __restrict__ Xs, const unsigned short* __restrict__ Ws,
    const float* __restrict__ bias, float* __restrict__ h,
    unsigned short* __restrict__ Ap) {
  __shared__ short Asm[128 * 64];
  __shared__ short Bsm[128 * 64];
  const int bid = blockIdx.x;               // 1024 blocks
  const int n = (bid >> 3) & 3;
  const int m = (bid & 7) * 32 + (bid >> 5);
  const int m0 = m * 128, j0 = n * 128;
  const int t = threadIdx.x;
  const int wid = t >> 6, wr = wid >> 1, wc = wid & 1;
  const int lr = t & 15, lg = (t >> 4) & 3;

  f32x4 acc[4][4];
#pragma unroll
  for (int mi = 0; mi < 4; ++mi)
#pragma unroll
    for (int ni = 0; ni < 4; ++ni) acc[mi][ni] = (f32x4){0.f, 0.f, 0.f, 0.f};

  for (int kt = 0; kt < 32; ++kt) {
    const int ph = kt >> 3, r64 = (kt & 7) * 64;
    const int koffA = (ph & 1) ? 512 + r64 : r64;   // hi, lo, hi, lo
    const int koffB = (ph & 2) ? 512 + r64 : r64;   // hi, hi, lo, lo
    const unsigned short* Ag = Xs + (size_t)m0 * 1024 + koffA;
    const unsigned short* Bg = Ws + (size_t)j0 * 1024 + koffB;
#pragma unroll
    for (int i = 0; i < 4; ++i) {
      const int chunk = i * 256 + t;
      const int r = chunk >> 3;
      const int c8s = (chunk & 7) ^ (r & 7);        // source-permute swizzle
      gload16(Ag + (size_t)r * 1024 + c8s * 8, &Asm[chunk * 8]);
      gload16(Bg + (size_t)r * 1024 + c8s * 8, &Bsm[chunk * 8]);
    }
    __syncthreads();
#pragma unroll
    for (int kk = 0; kk < 2; ++kk) {
      const int xk = (kk * 32 + lg * 8) ^ ((lr & 7) << 3);   // XOR'd read
      bf16x8 a[4], b[4];
#pragma unroll
      for (int mi = 0; mi < 4; ++mi)
        a[mi] = *(const bf16x8*)&Asm[(wr * 64 + mi * 16 + lr) * 64 + xk];
#pragma unroll
      for (int ni = 0; ni < 4; ++ni)
        b[ni] = *(const bf16x8*)&Bsm[(wc * 64 + ni * 16 + lr) * 64 + xk];
#pragma unroll
      for (int mi = 0; mi < 4; ++mi)
#pragma unroll
        for (int ni = 0; ni < 4; ++ni)
          acc[mi][ni] = __builtin_amdgcn_mfma_f32_16x16x32_bf16(a[mi], b[ni], acc[mi][ni], 0, 0, 0);
    }
    __syncthreads();
  }
#pragma unroll
  for (int ni = 0; ni < 4; ++ni) {
    const int col = j0 + wc * 64 + ni * 16 + lr;
    const float bb = bias[col];
#pragma unroll
    for (int mi = 0; mi < 4; ++mi)
#pragma unroll
      for (int jj = 0; jj < 4; ++jj) {
        const int row = m0 + wr * 64 + mi * 16 + lg * 4 + jj;
        const float v = acc[mi][ni][jj] + bb;
        h[(size_t)row * 512 + col] = v;
        const unsigned short hb = f2bf(v);
        Ap[(size_t)row * 1024 + col]       = hb;
        Ap[(size_t)row * 1024 + 512 + col] = f2bf(v - bf2f(hb));
      }
  }
}

// MFMA split-bf16 distance GEMM + per-row best/second argmin partials.
// grid 4096 (256 m x 16 n, XCD-swizzled), 4 waves 2x2; partial p = n*2+wc.
__global__ __launch_bounds__(256) void kdist_mfma(
    const unsigned short* __restrict__ Ap, const unsigned short* __restrict__ Bp,
    const float* __restrict__ enorms, float* __restrict__ pval,
    float* __restrict__ psec, int* __restrict__ pidx) {
  __shared__ short Asm[128 * 64];
  __shared__ short Bsm[128 * 64];
  const int bid = blockIdx.x;
  const int m = (bid & 7) * 32 + (bid >> 7);
  const int n = (bid >> 3) & 15;
  const int m0 = m * 128;
  const int n0 = n * 128;
  const int t = threadIdx.x;
  const int wid = t >> 6, wr = wid >> 1, wc = wid & 1;
  const int lr = t & 15, lg = (t >> 4) & 3;

  f32x4 acc[4][4];
#pragma unroll
  for (int mi = 0; mi < 4; ++mi)
#pragma unroll
    for (int ni = 0; ni < 4; ++ni) acc[mi][ni] = (f32x4){0.f, 0.f, 0.f, 0.f};

  for (int kt = 0; kt < 24; ++kt) {
    const int ph = kt >> 3, r64 = (kt & 7) * 64;
    const int koffA = (ph == 1) ? 512 + r64 : r64;  // h: hi, lo, hi
    const int koffB = (ph == 2) ? 512 + r64 : r64;  // e: hi, hi, lo
    const unsigned short* Ag = Ap + (size_t)m0 * 1024 + koffA;
    const unsigned short* Bg = Bp + (size_t)n0 * 1024 + koffB;
#pragma unroll
    for (int i = 0; i < 4; ++i) {
      const int chunk = i * 256 + t;
      const int r = chunk >> 3;
      const int c8s = (chunk & 7) ^ (r & 7);
      gload16(Ag + (size_t)r * 1024 + c8s * 8, &Asm[chunk * 8]);
      gload16(Bg + (size_t)r * 1024 + c8s * 8, &Bsm[chunk * 8]);
    }
    __syncthreads();
#pragma unroll
    for (int kk = 0; kk < 2; ++kk) {
      const int xk = (kk * 32 + lg * 8) ^ ((lr & 7) << 3);
      bf16x8 a[4], b[4];
#pragma unroll
      for (int mi = 0; mi < 4; ++mi)
        a[mi] = *(const bf16x8*)&Asm[(wr * 64 + mi * 16 + lr) * 64 + xk];
#pragma unroll
      for (int ni = 0; ni < 4; ++ni)
        b[ni] = *(const bf16x8*)&Bsm[(wc * 64 + ni * 16 + lr) * 64 + xk];
#pragma unroll
      for (int mi = 0; mi < 4; ++mi)
#pragma unroll
        for (int ni = 0; ni < 4; ++ni)
          acc[mi][ni] = __builtin_amdgcn_mfma_f32_16x16x32_bf16(a[mi], b[ni], acc[mi][ni], 0, 0, 0);
    }
    __syncthreads();
  }

  float en[4]; int kb[4];
#pragma unroll
  for (int ni = 0; ni < 4; ++ni) {
    kb[ni] = n0 + wc * 64 + ni * 16 + lr;
    en[ni] = enorms[kb[ni]];
  }
  const int p = n * 2 + wc;
#pragma unroll
  for (int mi = 0; mi < 4; ++mi)
#pragma unroll
    for (int j = 0; j < 4; ++j) {
      float bv = fmaf(-2.f, acc[mi][0][j], en[0]);
      int bk = kb[0];
      float sv = FLT_MAX;
#pragma unroll
      for (int ni = 1; ni < 4; ++ni) {
        const float v = fmaf(-2.f, acc[mi][ni][j], en[ni]);
        if (v < bv) { sv = bv; bv = v; bk = kb[ni]; }
        else sv = fminf(sv, v);
      }
#pragma unroll
      for (int msk = 1; msk < 16; msk <<= 1) {
        const float ob = __shfl_xor(bv, msk);
        const int   ok = __shfl_xor(bk, msk);
        const float os = __shfl_xor(sv, msk);
        if (ob < bv || (ob == bv && ok < bk)) { sv = fminf(bv, os); bv = ob; bk = ok; }
        else sv = fminf(sv, ob);
      }
      if (lr == 0) {
        const int row = m0 + wr * 64 + mi * 16 + lg * 4 + j;
        pval[p * NROWS + row] = bv;
        psec[p * NROWS + row] = sv;
        pidx[p * NROWS + row] = bk;
      }
    }
}

// merge 32 panel partials -> global best; flag ambiguous rows
__global__ __launch_bounds__(256) void kreduce(const float* __restrict__ pval,
    const float* __restrict__ psec, const int* __restrict__ pidx,
    int* __restrict__ idx, int* __restrict__ nflag, int* __restrict__ flags) {
  const int r = blockIdx.x * 256 + threadIdx.x;
  float bv = FLT_MAX, sv = FLT_MAX;
  int bk = 0;
#pragma unroll
  for (int p = 0; p < 32; ++p) {
    const float v1 = pval[p * NROWS + r];
    const int   k1 = pidx[p * NROWS + r];
    const float s1 = psec[p * NROWS + r];
    if (v1 < bv || (v1 == bv && k1 < bk)) { sv = fminf(bv, s1); bv = v1; bk = k1; }
    else sv = fminf(sv, v1);
  }
  idx[r] = bk;
  if (sv - bv < RESCORE_EPS) {
    const int pos = atomicAdd(nflag, 1);
    flags[pos] = r;
  }
}

// fp32 rescore for flagged rows using ref-grade stored h.
// 8 rows/block staged in LDS; wave w sweeps codes [w*512,(w+1)*512),
// lane owns d-slice (coalesced emb reads) + butterfly reduce.
__global__ __launch_bounds__(256) void krescore(const float* __restrict__ h,
    const float* __restrict__ emb, const float* __restrict__ enorms,
    const int* __restrict__ flags, const int* __restrict__ nflag,
    int* __restrict__ idx) {
  __shared__ float hr[8][512];
  __shared__ float wbv[4][8];
  __shared__ int   wbk[4][8];
  const int t = threadIdx.x;
  const int w = t >> 6;
  const int l = t & 63;
  const int nf = *nflag;
  for (int g = blockIdx.x; g * 8 < nf; g += gridDim.x) {
    __syncthreads();
    const int rows = min(8, nf - g * 8);
    for (int i = t; i < rows * 128; i += 256) {
      const int rr = i >> 7;
      const int c4 = (i & 127) << 2;
      const int r = flags[g * 8 + rr];
      *(float4*)&hr[rr][c4] = *(const float4*)&h[(size_t)r * 512 + c4];
    }
    __syncthreads();
    float bv[8]; int bk[8];
#pragma unroll
    for (int rr = 0; rr < 8; ++rr) { bv[rr] = FLT_MAX; bk[rr] = 0; }
    for (int c = w * 512; c < w * 512 + 512; ++c) {
      const float4 e0 = *(const float4*)&emb[(size_t)c * 512 + l * 8];
      const float4 e1 = *(const float4*)&emb[(size_t)c * 512 + l * 8 + 4];
      float dot[8];
#pragma unroll
      for (int rr = 0; rr < 8; ++rr) {
        const float4 h0 = *(const float4*)&hr[rr][l * 8];
        const float4 h1 = *(const float4*)&hr[rr][l * 8 + 4];
        dot[rr] = h0.x * e0.x + h0.y * e0.y + h0.z * e0.z + h0.w * e0.w
                + h1.x * e1.x + h1.y * e1.y + h1.z * e1.z + h1.w * e1.w;
      }
#pragma unroll
      for (int m = 1; m < 64; m <<= 1)
#pragma unroll
        for (int rr = 0; rr < 8; ++rr) dot[rr] += __shfl_xor(dot[rr], m);
      const float en = enorms[c];
#pragma unroll
      for (int rr = 0; rr < 8; ++rr) {
        const float v = fmaf(-2.f, dot[rr], en);
        if (v < bv[rr]) { bv[rr] = v; bk[rr] = c; }
      }
    }
    if (l == 0) {
#pragma unroll
      for (int rr = 0; rr < 8; ++rr) { wbv[w][rr] = bv[rr]; wbk[w][rr] = bk[rr]; }
    }
    __syncthreads();
    if (t < rows) {
      float fbv = wbv[0][t]; int fbk = wbk[0][t];
#pragma unroll
      for (int ww = 1; ww < 4; ++ww) {
        const float v = wbv[ww][t]; const int k = wbk[ww][t];
        if (v < fbv || (v == fbv && k < fbk)) { fbv = v; fbk = k; }
      }
      idx[flags[g * 8 + t]] = fbk;
    }
  }
}

__global__ __launch_bounds__(256) void kquant(const float* __restrict__ h,
    const float* __restrict__ emb, const int* __restrict__ idx,
    float* __restrict__ qout, double* __restrict__ loss_accum) {
  const int tid = blockIdx.x * 256 + threadIdx.x;
  float ls = 0.f;
#pragma unroll
  for (int i = 0; i < 4; ++i) {
    const int f = tid + i * 4194304;
    const int n = f >> 9;
    const int c = f & 511;
    const float hv = h[f];
    const float ev = emb[(size_t)idx[n] * DDIM + c];
    qout[f] = hv + (ev - hv);
    const float d = ev - hv;
    ls = fmaf(d, d, ls);
  }
  double s = (double)ls;
#pragma unroll
  for (int off = 32; off > 0; off >>= 1) s += __shfl_down(s, off);
  __shared__ double sred[4];
  if ((threadIdx.x & 63) == 0) sred[threadIdx.x >> 6] = s;
  __syncthreads();
  if (threadIdx.x == 0)
    atomicAdd(loss_accum, sred[0] + sred[1] + sred[2] + sred[3]);
}

__global__ __launch_bounds__(256) void khist(const int* __restrict__ idx,
                                             int* __restrict__ counts) {
  const int n = blockIdx.x * 256 + threadIdx.x;
  atomicAdd(&counts[idx[n]], 1);
}

__global__ __launch_bounds__(256) void kenc(const int* __restrict__ idx,
                                            float2* __restrict__ out2) {
  const int nt = 2048 * 256;
  for (int f2 = blockIdx.x * 256 + threadIdx.x; f2 < 33554432; f2 += nt) {
    const int n  = f2 >> 10;
    const int k  = (f2 & 1023) << 1;
    const int in = idx[n];
    out2[f2] = make_float2(in == k ? 1.f : 0.f, in == (k + 1) ? 1.f : 0.f);
  }
}

__global__ __launch_bounds__(256) void kfinal(const double* __restrict__ loss_accum,
    const int* __restrict__ counts, float* __restrict__ out) {
  __shared__ double sred[256];
  const int t = threadIdx.x;
  double s = 0.0;
  for (int k = t; k < KCODES; k += 256) {
    const double p = counts[k] / 32768.0;
    s += p * log(p + 1e-10);
  }
  sred[t] = s;
  __syncthreads();
  for (int off = 128; off > 0; off >>= 1) {
    if (t < off) sred[t] += sred[t + off];
    __syncthreads();
  }
  if (t == 0) {
    out[0]        = (float)(0.25 * loss_accum[0] / (32768.0 * 512.0));
    out[OUT_PERP] = (float)exp(-sred[0]);
  }
}

extern "C" void kernel_launch(void* const* d_in, const int* in_sizes, int n_in,
                              void* d_out, int out_size, void* d_ws, size_t ws_size,
                              hipStream_t stream) {
  const float* x0  = (const float*)d_in[0];
  const float* x1  = (const float*)d_in[1];
  const float* W   = (const float*)d_in[2];
  const float* b   = (const float*)d_in[3];
  const float* emb = (const float*)d_in[4];
  float* out = (float*)d_out;
  float* S   = out + OUT_ENC + 2;

  unsigned short* Ap = (unsigned short*)(S + AP_OFF);
  unsigned short* Bp = (unsigned short*)(S + BP_OFF);
  unsigned short* Xs = (unsigned short*)(S + XS_OFF);
  unsigned short* Ws = (unsigned short*)(S + WS_OFF);
  int* pidx = (int*)(S + PIDX_OFF);

  double* loss_accum = (double*)d_ws;
  int* nflag  = (int*)((char*)d_ws + 8);
  int* counts = (int*)((char*)d_ws + 16);
  int* idx    = (int*)((char*)d_ws + 8208);
  int* flags  = (int*)((char*)d_ws + 139280);

  hipMemsetAsync(d_ws, 0, 8208, stream);

  ksplit_half<<<8192, 256, 0, stream>>>(x0, Xs, 0);
  ksplit_half<<<8192, 256, 0, stream>>>(x1, Xs, 256);
  ksplit_full<<<256,  256, 0, stream>>>(W, Ws);
  ksplit_full<<<1024, 256, 0, stream>>>(emb, Bp);
  kenorm<<<2048, 64, 0, stream>>>(emb, S + ENORM_OFF);
  kgemm1_mfma<<<1024, 256, 0, stream>>>(Xs, Ws, b, S + H_OFF, Ap);
  kdist_mfma<<<4096, 256, 0, stream>>>(Ap, Bp, S + ENORM_OFF,
                                       S + PVAL_OFF, S + PSEC_OFF, pidx);
  kreduce<<<128, 256, 0, stream>>>(S + PVAL_OFF, S + PSEC_OFF, pidx, idx, nflag, flags);
  krescore<<<128, 256, 0, stream>>>(S + H_OFF, emb, S + ENORM_OFF,
                                    flags, nflag, idx);
  kquant<<<16384, 256, 0, stream>>>(S + H_OFF, emb, idx, out + OUT_Q, loss_accum);
  khist<<<128, 256, 0, stream>>>(idx, counts);
  kenc<<<2048, 256, 0, stream>>>(idx, (float2*)(out + OUT_ENC));
  kfinal<<<1, 256, 0, stream>>>(loss_accum, counts, out);
}

// Round 6
// 889.710 us; speedup vs baseline: 2.0044x; 2.0044x over previous
//
#include <hip/hip_runtime.h>
#include <cfloat>
#include <cmath>

#define NROWS 32768
#define DDIM  512
#define KCODES 2048

// output layout (floats): [loss][q_st N*512][perplexity][encodings N*K]
#define OUT_Q    1
#define OUT_PERP 16777217
#define OUT_ENC  16777218

// scratch offsets in float slots, relative to S = d_out + OUT_ENC + 2
// (capacity 67,108,862 float slots inside the encodings region)
#define H_OFF     0           // 16,777,216  h fp32 [32768][512]
#define AP_OFF    16777216    // 16,777,216  h split bf16 [32768][1024] (hi|lo)
#define BP_OFF    33554432    //  1,048,576  emb split bf16 [2048][1024]
#define XS_OFF    34603008    // 16,777,216  X split bf16 [32768][1024]
#define WS_OFF    51380224    //    262,144  W split bf16 [512][1024]
#define ENORM_OFF 51642368    //      2,048
#define PVAL_OFF  51644416    //  1,048,576 (32 x 32768)
#define PSEC_OFF  52692992    //  1,048,576
#define PIDX_OFF  53741568    //  1,048,576 -> end 54,790,144

#define RESCORE_EPS 0.02f

typedef __attribute__((ext_vector_type(8))) short  bf16x8;
typedef __attribute__((ext_vector_type(4))) float  f32x4;

__device__ __forceinline__ unsigned short f2bf(float f) {
  unsigned u = __float_as_uint(f);
  unsigned r = (u + 0x7FFF + ((u >> 16) & 1)) >> 16;
  return (unsigned short)r;
}
__device__ __forceinline__ float bf2f(unsigned short h) {
  return __uint_as_float(((unsigned)h) << 16);
}
__device__ __forceinline__ void gload16(const void* g, void* l) {
  __builtin_amdgcn_global_load_lds(
      (const __attribute__((address_space(1))) unsigned int*)g,
      (__attribute__((address_space(3))) unsigned int*)l, 16, 0, 0);
}
__device__ __forceinline__ ushort4 hi4(float4 v) {
  return make_ushort4(f2bf(v.x), f2bf(v.y), f2bf(v.z), f2bf(v.w));
}
__device__ __forceinline__ ushort4 lo4(float4 v, ushort4 h) {
  return make_ushort4(f2bf(v.x - bf2f(h.x)), f2bf(v.y - bf2f(h.y)),
                      f2bf(v.z - bf2f(h.z)), f2bf(v.w - bf2f(h.w)));
}

// fp32 [R][256] half -> hi/lo into Xs [R][1024] at column offset colOff
__global__ __launch_bounds__(256) void ksplit_half(const float* __restrict__ src,
    unsigned short* __restrict__ Xs, int colOff) {
  const int tid = blockIdx.x * 256 + threadIdx.x;   // 8192 blocks
  const int n  = tid >> 6;
  const int c4 = (tid & 63) * 4;
  const float4 v = *(const float4*)&src[(size_t)n * 256 + c4];
  const ushort4 h = hi4(v);
  unsigned short* row = Xs + (size_t)n * 1024;
  *(ushort4*)&row[colOff + c4]       = h;
  *(ushort4*)&row[512 + colOff + c4] = lo4(v, h);
}

// fp32 [R][512] -> hi/lo into dst [R][1024]
__global__ __launch_bounds__(256) void ksplit_full(const float* __restrict__ src,
    unsigned short* __restrict__ dst) {
  const int tid = blockIdx.x * 256 + threadIdx.x;
  const int r  = tid >> 7;
  const int c4 = (tid & 127) * 4;
  const float4 v = *(const float4*)&src[(size_t)r * 512 + c4];
  const ushort4 h = hi4(v);
  unsigned short* row = dst + (size_t)r * 1024;
  *(ushort4*)&row[c4]       = h;
  *(ushort4*)&row[512 + c4] = lo4(v, h);
}

__global__ __launch_bounds__(64) void kenorm(const float* __restrict__ emb,
                                             float* __restrict__ enorms) {
  const int k = blockIdx.x;
  const int t = threadIdx.x;
  float s = 0.f;
#pragma unroll
  for (int i = 0; i < 8; ++i) {
    const float v = emb[k * DDIM + t + i * 64];
    s = fmaf(v, v, s);
  }
#pragma unroll
  for (int off = 32; off > 0; off >>= 1) s += __shfl_down(s, off);
  if (t == 0) enorms[k] = s;
}

// h = X @ W^T + b via split-bf16 MFMA, 4-term (hi*hi, lo*hi, hi*lo, lo*lo):
// h is ref-grade fp32 (residual ~1e-7/comp). Writes h fp32 and Ap=split(h).
__global__ __launch_bounds__(256) void kgemm1_mfma(
    const unsigned short* __restrict__ Xs, const unsigned short* __restrict__ Ws,
    const float* __restrict__ bias, float* __restrict__ h,
    unsigned short* __restrict__ Ap) {
  __shared__ short Asm[128 * 64];
  __shared__ short Bsm[128 * 64];
  const int bid = blockIdx.x;               // 1024 blocks
  const int n = (bid >> 3) & 3;
  const int m = (bid & 7) * 32 + (bid >> 5);
  const int m0 = m * 128, j0 = n * 128;
  const int t = threadIdx.x;
  const int wid = t >> 6, wr = wid >> 1, wc = wid & 1;
  const int lr = t & 15, lg = (t >> 4) & 3;

  f32x4 acc[4][4];
#pragma unroll
  for (int mi = 0; mi < 4; ++mi)
#pragma unroll
    for (int ni = 0; ni < 4; ++ni) acc[mi][ni] = (f32x4){0.f, 0.f, 0.f, 0.f};

  for (int kt = 0; kt < 32; ++kt) {
    const int ph = kt >> 3, r64 = (kt & 7) * 64;
    const int koffA = (ph & 1) ? 512 + r64 : r64;   // hi, lo, hi, lo
    const int koffB = (ph & 2) ? 512 + r64 : r64;   // hi, hi, lo, lo
    const unsigned short* Ag = Xs + (size_t)m0 * 1024 + koffA;
    const unsigned short* Bg = Ws + (size_t)j0 * 1024 + koffB;
#pragma unroll
    for (int i = 0; i < 4; ++i) {
      const int chunk = i * 256 + t;
      const int r = chunk >> 3;
      const int c8s = (chunk & 7) ^ (r & 7);        // source-permute swizzle
      gload16(Ag + (size_t)r * 1024 + c8s * 8, &Asm[chunk * 8]);
      gload16(Bg + (size_t)r * 1024 + c8s * 8, &Bsm[chunk * 8]);
    }
    __syncthreads();
#pragma unroll
    for (int kk = 0; kk < 2; ++kk) {
      const int xk = (kk * 32 + lg * 8) ^ ((lr & 7) << 3);   // XOR'd read
      bf16x8 a[4], b[4];
#pragma unroll
      for (int mi = 0; mi < 4; ++mi)
        a[mi] = *(const bf16x8*)&Asm[(wr * 64 + mi * 16 + lr) * 64 + xk];
#pragma unroll
      for (int ni = 0; ni < 4; ++ni)
        b[ni] = *(const bf16x8*)&Bsm[(wc * 64 + ni * 16 + lr) * 64 + xk];
#pragma unroll
      for (int mi = 0; mi < 4; ++mi)
#pragma unroll
        for (int ni = 0; ni < 4; ++ni)
          acc[mi][ni] = __builtin_amdgcn_mfma_f32_16x16x32_bf16(a[mi], b[ni], acc[mi][ni], 0, 0, 0);
    }
    __syncthreads();
  }
#pragma unroll
  for (int ni = 0; ni < 4; ++ni) {
    const int col = j0 + wc * 64 + ni * 16 + lr;
    const float bb = bias[col];
#pragma unroll
    for (int mi = 0; mi < 4; ++mi)
#pragma unroll
      for (int jj = 0; jj < 4; ++jj) {
        const int row = m0 + wr * 64 + mi * 16 + lg * 4 + jj;
        const float v = acc[mi][ni][jj] + bb;
        h[(size_t)row * 512 + col] = v;
        const unsigned short hb = f2bf(v);
        Ap[(size_t)row * 1024 + col]       = hb;
        Ap[(size_t)row * 1024 + 512 + col] = f2bf(v - bf2f(hb));
      }
  }
}

// MFMA split-bf16 distance GEMM + per-row best/second argmin partials.
// grid 4096 (256 m x 16 n, XCD-swizzled), 4 waves 2x2; partial p = n*2+wc.
__global__ __launch_bounds__(256) void kdist_mfma(
    const unsigned short* __restrict__ Ap, const unsigned short* __restrict__ Bp,
    const float* __restrict__ enorms, float* __restrict__ pval,
    float* __restrict__ psec, int* __restrict__ pidx) {
  __shared__ short Asm[128 * 64];
  __shared__ short Bsm[128 * 64];
  const int bid = blockIdx.x;
  const int m = (bid & 7) * 32 + (bid >> 7);
  const int n = (bid >> 3) & 15;
  const int m0 = m * 128;
  const int n0 = n * 128;
  const int t = threadIdx.x;
  const int wid = t >> 6, wr = wid >> 1, wc = wid & 1;
  const int lr = t & 15, lg = (t >> 4) & 3;

  f32x4 acc[4][4];
#pragma unroll
  for (int mi = 0; mi < 4; ++mi)
#pragma unroll
    for (int ni = 0; ni < 4; ++ni) acc[mi][ni] = (f32x4){0.f, 0.f, 0.f, 0.f};

  for (int kt = 0; kt < 24; ++kt) {
    const int ph = kt >> 3, r64 = (kt & 7) * 64;
    const int koffA = (ph == 1) ? 512 + r64 : r64;  // h: hi, lo, hi
    const int koffB = (ph == 2) ? 512 + r64 : r64;  // e: hi, hi, lo
    const unsigned short* Ag = Ap + (size_t)m0 * 1024 + koffA;
    const unsigned short* Bg = Bp + (size_t)n0 * 1024 + koffB;
#pragma unroll
    for (int i = 0; i < 4; ++i) {
      const int chunk = i * 256 + t;
      const int r = chunk >> 3;
      const int c8s = (chunk & 7) ^ (r & 7);
      gload16(Ag + (size_t)r * 1024 + c8s * 8, &Asm[chunk * 8]);
      gload16(Bg + (size_t)r * 1024 + c8s * 8, &Bsm[chunk * 8]);
    }
    __syncthreads();
#pragma unroll
    for (int kk = 0; kk < 2; ++kk) {
      const int xk = (kk * 32 + lg * 8) ^ ((lr & 7) << 3);
      bf16x8 a[4], b[4];
#pragma unroll
      for (int mi = 0; mi < 4; ++mi)
        a[mi] = *(const bf16x8*)&Asm[(wr * 64 + mi * 16 + lr) * 64 + xk];
#pragma unroll
      for (int ni = 0; ni < 4; ++ni)
        b[ni] = *(const bf16x8*)&Bsm[(wc * 64 + ni * 16 + lr) * 64 + xk];
#pragma unroll
      for (int mi = 0; mi < 4; ++mi)
#pragma unroll
        for (int ni = 0; ni < 4; ++ni)
          acc[mi][ni] = __builtin_amdgcn_mfma_f32_16x16x32_bf16(a[mi], b[ni], acc[mi][ni], 0, 0, 0);
    }
    __syncthreads();
  }

  float en[4]; int kb[4];
#pragma unroll
  for (int ni = 0; ni < 4; ++ni) {
    kb[ni] = n0 + wc * 64 + ni * 16 + lr;
    en[ni] = enorms[kb[ni]];
  }
  const int p = n * 2 + wc;
#pragma unroll
  for (int mi = 0; mi < 4; ++mi)
#pragma unroll
    for (int j = 0; j < 4; ++j) {
      float bv = fmaf(-2.f, acc[mi][0][j], en[0]);
      int bk = kb[0];
      float sv = FLT_MAX;
#pragma unroll
      for (int ni = 1; ni < 4; ++ni) {
        const float v = fmaf(-2.f, acc[mi][ni][j], en[ni]);
        if (v < bv) { sv = bv; bv = v; bk = kb[ni]; }
        else sv = fminf(sv, v);
      }
#pragma unroll
      for (int msk = 1; msk < 16; msk <<= 1) {
        const float ob = __shfl_xor(bv, msk);
        const int   ok = __shfl_xor(bk, msk);
        const float os = __shfl_xor(sv, msk);
        if (ob < bv || (ob == bv && ok < bk)) { sv = fminf(bv, os); bv = ob; bk = ok; }
        else sv = fminf(sv, ob);
      }
      if (lr == 0) {
        const int row = m0 + wr * 64 + mi * 16 + lg * 4 + j;
        pval[p * NROWS + row] = bv;
        psec[p * NROWS + row] = sv;
        pidx[p * NROWS + row] = bk;
      }
    }
}

// merge 32 panel partials -> global best; flag ambiguous rows
__global__ __launch_bounds__(256) void kreduce(const float* __restrict__ pval,
    const float* __restrict__ psec, const int* __restrict__ pidx,
    int* __restrict__ idx, int* __restrict__ nflag, int* __restrict__ flags) {
  const int r = blockIdx.x * 256 + threadIdx.x;
  float bv = FLT_MAX, sv = FLT_MAX;
  int bk = 0;
#pragma unroll
  for (int p = 0; p < 32; ++p) {
    const float v1 = pval[p * NROWS + r];
    const int   k1 = pidx[p * NROWS + r];
    const float s1 = psec[p * NROWS + r];
    if (v1 < bv || (v1 == bv && k1 < bk)) { sv = fminf(bv, s1); bv = v1; bk = k1; }
    else sv = fminf(sv, v1);
  }
  idx[r] = bk;
  if (sv - bv < RESCORE_EPS) {
    const int pos = atomicAdd(nflag, 1);
    flags[pos] = r;
  }
}

// fp32 rescore, one block per flagged row (wide & shallow):
// h row staged in LDS (broadcast reads); thread t dots codes t+256j,
// 4 independent accumulators, no cross-lane ops; LDS tree argmin.
__global__ __launch_bounds__(256) void krescore(const float* __restrict__ h,
    const float* __restrict__ emb, const float* __restrict__ enorms,
    const int* __restrict__ flags, const int* __restrict__ nflag,
    int* __restrict__ idx) {
  __shared__ float hr[512];
  __shared__ float rv[256];
  __shared__ int   rk[256];
  const int t = threadIdx.x;
  const int nf = *nflag;
  for (int f = blockIdx.x; f < nf; f += gridDim.x) {
    __syncthreads();
    const int r = flags[f];
    if (t < 128) ((float4*)hr)[t] = ((const float4*)(h + (size_t)r * 512))[t];
    __syncthreads();
    float bv = FLT_MAX; int bk = 0;
#pragma unroll
    for (int j = 0; j < 8; ++j) {
      const int c = t + j * 256;
      const float* er = emb + (size_t)c * 512;
      float d0 = 0.f, d1 = 0.f, d2 = 0.f, d3 = 0.f;
#pragma unroll 4
      for (int d = 0; d < 512; d += 16) {
        const float4 e0 = *(const float4*)&er[d];
        const float4 e1 = *(const float4*)&er[d + 4];
        const float4 e2 = *(const float4*)&er[d + 8];
        const float4 e3 = *(const float4*)&er[d + 12];
        d0 = fmaf(hr[d+0],  e0.x, d0); d0 = fmaf(hr[d+1],  e0.y, d0);
        d0 = fmaf(hr[d+2],  e0.z, d0); d0 = fmaf(hr[d+3],  e0.w, d0);
        d1 = fmaf(hr[d+4],  e1.x, d1); d1 = fmaf(hr[d+5],  e1.y, d1);
        d1 = fmaf(hr[d+6],  e1.z, d1); d1 = fmaf(hr[d+7],  e1.w, d1);
        d2 = fmaf(hr[d+8],  e2.x, d2); d2 = fmaf(hr[d+9],  e2.y, d2);
        d2 = fmaf(hr[d+10], e2.z, d2); d2 = fmaf(hr[d+11], e2.w, d2);
        d3 = fmaf(hr[d+12], e3.x, d3); d3 = fmaf(hr[d+13], e3.y, d3);
        d3 = fmaf(hr[d+14], e3.z, d3); d3 = fmaf(hr[d+15], e3.w, d3);
      }
      const float dot = (d0 + d1) + (d2 + d3);
      const float v = fmaf(-2.f, dot, enorms[c]);
      if (v < bv) { bv = v; bk = c; }
    }
    rv[t] = bv; rk[t] = bk;
    __syncthreads();
    for (int off = 128; off > 0; off >>= 1) {
      if (t < off) {
        const float v2 = rv[t + off];
        const int   k2 = rk[t + off];
        if (v2 < rv[t] || (v2 == rv[t] && k2 < rk[t])) { rv[t] = v2; rk[t] = k2; }
      }
      __syncthreads();
    }
    if (t == 0) idx[r] = rk[0];
  }
}

__global__ __launch_bounds__(256) void kquant(const float* __restrict__ h,
    const float* __restrict__ emb, const int* __restrict__ idx,
    float* __restrict__ qout, double* __restrict__ loss_accum) {
  const int tid = blockIdx.x * 256 + threadIdx.x;
  float ls = 0.f;
#pragma unroll
  for (int i = 0; i < 4; ++i) {
    const int f = tid + i * 4194304;
    const int n = f >> 9;
    const int c = f & 511;
    const float hv = h[f];
    const float ev = emb[(size_t)idx[n] * DDIM + c];
    qout[f] = hv + (ev - hv);
    const float d = ev - hv;
    ls = fmaf(d, d, ls);
  }
  double s = (double)ls;
#pragma unroll
  for (int off = 32; off > 0; off >>= 1) s += __shfl_down(s, off);
  __shared__ double sred[4];
  if ((threadIdx.x & 63) == 0) sred[threadIdx.x >> 6] = s;
  __syncthreads();
  if (threadIdx.x == 0)
    atomicAdd(loss_accum, sred[0] + sred[1] + sred[2] + sred[3]);
}

__global__ __launch_bounds__(256) void khist(const int* __restrict__ idx,
                                             int* __restrict__ counts) {
  const int n = blockIdx.x * 256 + threadIdx.x;
  atomicAdd(&counts[idx[n]], 1);
}

__global__ __launch_bounds__(256) void kenc(const int* __restrict__ idx,
                                            float2* __restrict__ out2) {
  const int nt = 2048 * 256;
  for (int f2 = blockIdx.x * 256 + threadIdx.x; f2 < 33554432; f2 += nt) {
    const int n  = f2 >> 10;
    const int k  = (f2 & 1023) << 1;
    const int in = idx[n];
    out2[f2] = make_float2(in == k ? 1.f : 0.f, in == (k + 1) ? 1.f : 0.f);
  }
}

__global__ __launch_bounds__(256) void kfinal(const double* __restrict__ loss_accum,
    const int* __restrict__ counts, float* __restrict__ out) {
  __shared__ double sred[256];
  const int t = threadIdx.x;
  double s = 0.0;
  for (int k = t; k < KCODES; k += 256) {
    const double p = counts[k] / 32768.0;
    s += p * log(p + 1e-10);
  }
  sred[t] = s;
  __syncthreads();
  for (int off = 128; off > 0; off >>= 1) {
    if (t < off) sred[t] += sred[t + off];
    __syncthreads();
  }
  if (t == 0) {
    out[0]        = (float)(0.25 * loss_accum[0] / (32768.0 * 512.0));
    out[OUT_PERP] = (float)exp(-sred[0]);
  }
}

extern "C" void kernel_launch(void* const* d_in, const int* in_sizes, int n_in,
                              void* d_out, int out_size, void* d_ws, size_t ws_size,
                              hipStream_t stream) {
  const float* x0  = (const float*)d_in[0];
  const float* x1  = (const float*)d_in[1];
  const float* W   = (const float*)d_in[2];
  const float* b   = (const float*)d_in[3];
  const float* emb = (const float*)d_in[4];
  float* out = (float*)d_out;
  float* S   = out + OUT_ENC + 2;

  unsigned short* Ap = (unsigned short*)(S + AP_OFF);
  unsigned short* Bp = (unsigned short*)(S + BP_OFF);
  unsigned short* Xs = (unsigned short*)(S + XS_OFF);
  unsigned short* Ws = (unsigned short*)(S + WS_OFF);
  int* pidx = (int*)(S + PIDX_OFF);

  double* loss_accum = (double*)d_ws;
  int* nflag  = (int*)((char*)d_ws + 8);
  int* counts = (int*)((char*)d_ws + 16);
  int* idx    = (int*)((char*)d_ws + 8208);
  int* flags  = (int*)((char*)d_ws + 139280);

  hipMemsetAsync(d_ws, 0, 8208, stream);

  ksplit_half<<<8192, 256, 0, stream>>>(x0, Xs, 0);
  ksplit_half<<<8192, 256, 0, stream>>>(x1, Xs, 256);
  ksplit_full<<<256,  256, 0, stream>>>(W, Ws);
  ksplit_full<<<1024, 256, 0, stream>>>(emb, Bp);
  kenorm<<<2048, 64, 0, stream>>>(emb, S + ENORM_OFF);
  kgemm1_mfma<<<1024, 256, 0, stream>>>(Xs, Ws, b, S + H_OFF, Ap);
  kdist_mfma<<<4096, 256, 0, stream>>>(Ap, Bp, S + ENORM_OFF,
                                       S + PVAL_OFF, S + PSEC_OFF, pidx);
  kreduce<<<128, 256, 0, stream>>>(S + PVAL_OFF, S + PSEC_OFF, pidx, idx, nflag, flags);
  krescore<<<256, 256, 0, stream>>>(S + H_OFF, emb, S + ENORM_OFF,
                                    flags, nflag, idx);
  kquant<<<16384, 256, 0, stream>>>(S + H_OFF, emb, idx, out + OUT_Q, loss_accum);
  khist<<<128, 256, 0, stream>>>(idx, counts);
  kenc<<<2048, 256, 0, stream>>>(idx, (float2*)(out + OUT_ENC));
  kfinal<<<1, 256, 0, stream>>>(loss_accum, counts, out);
}

// Round 7
// 875.756 us; speedup vs baseline: 2.0363x; 1.0159x over previous
//
#include <hip/hip_runtime.h>
#include <cfloat>
#include <cmath>

#define NROWS 32768
#define DDIM  512
#define KCODES 2048

// output layout (floats): [loss][q_st N*512][perplexity][encodings N*K]
#define OUT_Q    1
#define OUT_PERP 16777217
#define OUT_ENC  16777218

// scratch offsets in float slots, relative to S = d_out + OUT_ENC + 2
// (capacity 67,108,862 float slots inside the encodings region)
#define H_OFF     0           // 16,777,216  h fp32 [32768][512]
#define AP_OFF    16777216    // 16,777,216  h split bf16 [32768][1024] (hi|lo)
#define BP_OFF    33554432    //  1,048,576  emb split bf16 [2048][1024]
#define XS_OFF    34603008    // 16,777,216  X split bf16 [32768][1024]
#define WS_OFF    51380224    //    262,144  W split bf16 [512][1024]
#define ENORM_OFF 51642368    //      2,048
#define PVAL_OFF  51644416    //  1,048,576 (32 x 32768)
#define PSEC_OFF  52692992    //  1,048,576
#define PIDX_OFF  53741568    //  1,048,576
#define AG_OFF    54790144    //  8,388,608 (gathered rows bf16 [16384][1024])
#define PVAL2_OFF 63178752    //    524,288 (32 x 16384)
#define PSEC2_OFF 63703040    //    524,288
#define PIDX2_OFF 64227328    //    524,288 -> end 64,751,616

#define CAP1 16384            // stage-2 gather capacity
#define CAP2 4096             // stage-3 capacity
#define EPS1 0.2f             // 2-term flag margin (sigma_d2 ~ 0.03)
#define EPS2 0.02f            // 3-term flag margin (r3/r4-proven)

typedef __attribute__((ext_vector_type(8))) short  bf16x8;
typedef __attribute__((ext_vector_type(4))) float  f32x4;

__device__ __forceinline__ unsigned short f2bf(float f) {
  unsigned u = __float_as_uint(f);
  unsigned r = (u + 0x7FFF + ((u >> 16) & 1)) >> 16;
  return (unsigned short)r;
}
__device__ __forceinline__ float bf2f(unsigned short h) {
  return __uint_as_float(((unsigned)h) << 16);
}
__device__ __forceinline__ void gload16(const void* g, void* l) {
  __builtin_amdgcn_global_load_lds(
      (const __attribute__((address_space(1))) unsigned int*)g,
      (__attribute__((address_space(3))) unsigned int*)l, 16, 0, 0);
}
__device__ __forceinline__ ushort4 hi4(float4 v) {
  return make_ushort4(f2bf(v.x), f2bf(v.y), f2bf(v.z), f2bf(v.w));
}
__device__ __forceinline__ ushort4 lo4(float4 v, ushort4 h) {
  return make_ushort4(f2bf(v.x - bf2f(h.x)), f2bf(v.y - bf2f(h.y)),
                      f2bf(v.z - bf2f(h.z)), f2bf(v.w - bf2f(h.w)));
}

// fp32 [R][256] half -> hi/lo into Xs [R][1024] at column offset colOff
__global__ __launch_bounds__(256) void ksplit_half(const float* __restrict__ src,
    unsigned short* __restrict__ Xs, int colOff) {
  const int tid = blockIdx.x * 256 + threadIdx.x;   // 8192 blocks
  const int n  = tid >> 6;
  const int c4 = (tid & 63) * 4;
  const float4 v = *(const float4*)&src[(size_t)n * 256 + c4];
  const ushort4 h = hi4(v);
  unsigned short* row = Xs + (size_t)n * 1024;
  *(ushort4*)&row[colOff + c4]       = h;
  *(ushort4*)&row[512 + colOff + c4] = lo4(v, h);
}

// fp32 [R][512] -> hi/lo into dst [R][1024]
__global__ __launch_bounds__(256) void ksplit_full(const float* __restrict__ src,
    unsigned short* __restrict__ dst) {
  const int tid = blockIdx.x * 256 + threadIdx.x;
  const int r  = tid >> 7;
  const int c4 = (tid & 127) * 4;
  const float4 v = *(const float4*)&src[(size_t)r * 512 + c4];
  const ushort4 h = hi4(v);
  unsigned short* row = dst + (size_t)r * 1024;
  *(ushort4*)&row[c4]       = h;
  *(ushort4*)&row[512 + c4] = lo4(v, h);
}

__global__ __launch_bounds__(64) void kenorm(const float* __restrict__ emb,
                                             float* __restrict__ enorms) {
  const int k = blockIdx.x;
  const int t = threadIdx.x;
  float s = 0.f;
#pragma unroll
  for (int i = 0; i < 8; ++i) {
    const float v = emb[k * DDIM + t + i * 64];
    s = fmaf(v, v, s);
  }
#pragma unroll
  for (int off = 32; off > 0; off >>= 1) s += __shfl_down(s, off);
  if (t == 0) enorms[k] = s;
}

// h = X @ W^T + b via split-bf16 MFMA, 4-term (hi*hi, lo*hi, hi*lo, lo*lo):
// h is ref-grade fp32 (residual ~1e-7/comp). Writes h fp32 and Ap=split(h).
__global__ __launch_bounds__(256) void kgemm1_mfma(
    const unsigned short* __restrict__ Xs, const unsigned short* __restrict__ Ws,
    const float* __restrict__ bias, float* __restrict__ h,
    unsigned short* __restrict__ Ap) {
  __shared__ short Asm[128 * 64];
  __shared__ short Bsm[128 * 64];
  const int bid = blockIdx.x;               // 1024 blocks
  const int n = (bid >> 3) & 3;
  const int m = (bid & 7) * 32 + (bid >> 5);
  const int m0 = m * 128, j0 = n * 128;
  const int t = threadIdx.x;
  const int wid = t >> 6, wr = wid >> 1, wc = wid & 1;
  const int lr = t & 15, lg = (t >> 4) & 3;

  f32x4 acc[4][4];
#pragma unroll
  for (int mi = 0; mi < 4; ++mi)
#pragma unroll
    for (int ni = 0; ni < 4; ++ni) acc[mi][ni] = (f32x4){0.f, 0.f, 0.f, 0.f};

  for (int kt = 0; kt < 32; ++kt) {
    const int ph = kt >> 3, r64 = (kt & 7) * 64;
    const int koffA = (ph & 1) ? 512 + r64 : r64;   // hi, lo, hi, lo
    const int koffB = (ph & 2) ? 512 + r64 : r64;   // hi, hi, lo, lo
    const unsigned short* Ag = Xs + (size_t)m0 * 1024 + koffA;
    const unsigned short* Bg = Ws + (size_t)j0 * 1024 + koffB;
#pragma unroll
    for (int i = 0; i < 4; ++i) {
      const int chunk = i * 256 + t;
      const int r = chunk >> 3;
      const int c8s = (chunk & 7) ^ (r & 7);        // source-permute swizzle
      gload16(Ag + (size_t)r * 1024 + c8s * 8, &Asm[chunk * 8]);
      gload16(Bg + (size_t)r * 1024 + c8s * 8, &Bsm[chunk * 8]);
    }
    __syncthreads();
#pragma unroll
    for (int kk = 0; kk < 2; ++kk) {
      const int xk = (kk * 32 + lg * 8) ^ ((lr & 7) << 3);   // XOR'd read
      bf16x8 a[4], b[4];
#pragma unroll
      for (int mi = 0; mi < 4; ++mi)
        a[mi] = *(const bf16x8*)&Asm[(wr * 64 + mi * 16 + lr) * 64 + xk];
#pragma unroll
      for (int ni = 0; ni < 4; ++ni)
        b[ni] = *(const bf16x8*)&Bsm[(wc * 64 + ni * 16 + lr) * 64 + xk];
#pragma unroll
      for (int mi = 0; mi < 4; ++mi)
#pragma unroll
        for (int ni = 0; ni < 4; ++ni)
          acc[mi][ni] = __builtin_amdgcn_mfma_f32_16x16x32_bf16(a[mi], b[ni], acc[mi][ni], 0, 0, 0);
    }
    __syncthreads();
  }
#pragma unroll
  for (int ni = 0; ni < 4; ++ni) {
    const int col = j0 + wc * 64 + ni * 16 + lr;
    const float bb = bias[col];
#pragma unroll
    for (int mi = 0; mi < 4; ++mi)
#pragma unroll
      for (int jj = 0; jj < 4; ++jj) {
        const int row = m0 + wr * 64 + mi * 16 + lg * 4 + jj;
        const float v = acc[mi][ni][jj] + bb;
        h[(size_t)row * 512 + col] = v;
        const unsigned short hb = f2bf(v);
        Ap[(size_t)row * 1024 + col]       = hb;
        Ap[(size_t)row * 1024 + 512 + col] = f2bf(v - bf2f(hb));
      }
  }
}

// MFMA split-bf16 distance GEMM + per-row best/second argmin partials.
// KSTEPS=16: 2-term (A: hi,lo; B: hi,hi)  KSTEPS=24: 3-term (A: hi,lo,hi; B: hi,hi,lo)
// GATED: simple m-map + early-exit on (*nflag+127)/128 active panels.
// partial slot p = n*2 + wc; stride mrows.
template<int KSTEPS, bool GATED>
__global__ __launch_bounds__(256) void kdist_t(
    const unsigned short* __restrict__ A, const unsigned short* __restrict__ B,
    const float* __restrict__ enorms, float* __restrict__ pval,
    float* __restrict__ psec, int* __restrict__ pidx,
    const int* __restrict__ nflag, int mrows) {
  __shared__ short Asm[128 * 64];
  __shared__ short Bsm[128 * 64];
  const int bid = blockIdx.x;
  int m, n;
  if (GATED) {
    m = bid >> 4;
    n = bid & 15;
    const int nf = min(*nflag, CAP1);
    if (m >= ((nf + 127) >> 7)) return;
  } else {
    m = (bid & 7) * 32 + (bid >> 7);
    n = (bid >> 3) & 15;
  }
  const int m0 = m * 128;
  const int n0 = n * 128;
  const int t = threadIdx.x;
  const int wid = t >> 6, wr = wid >> 1, wc = wid & 1;
  const int lr = t & 15, lg = (t >> 4) & 3;

  f32x4 acc[4][4];
#pragma unroll
  for (int mi = 0; mi < 4; ++mi)
#pragma unroll
    for (int ni = 0; ni < 4; ++ni) acc[mi][ni] = (f32x4){0.f, 0.f, 0.f, 0.f};

  for (int kt = 0; kt < KSTEPS; ++kt) {
    const int ph = kt >> 3, r64 = (kt & 7) * 64;
    const int koffA = (ph == 1) ? 512 + r64 : r64;
    const int koffB = (ph == 2) ? 512 + r64 : r64;
    const unsigned short* Agp = A + (size_t)m0 * 1024 + koffA;
    const unsigned short* Bgp = B + (size_t)n0 * 1024 + koffB;
#pragma unroll
    for (int i = 0; i < 4; ++i) {
      const int chunk = i * 256 + t;
      const int r = chunk >> 3;
      const int c8s = (chunk & 7) ^ (r & 7);
      gload16(Agp + (size_t)r * 1024 + c8s * 8, &Asm[chunk * 8]);
      gload16(Bgp + (size_t)r * 1024 + c8s * 8, &Bsm[chunk * 8]);
    }
    __syncthreads();
#pragma unroll
    for (int kk = 0; kk < 2; ++kk) {
      const int xk = (kk * 32 + lg * 8) ^ ((lr & 7) << 3);
      bf16x8 a[4], b[4];
#pragma unroll
      for (int mi = 0; mi < 4; ++mi)
        a[mi] = *(const bf16x8*)&Asm[(wr * 64 + mi * 16 + lr) * 64 + xk];
#pragma unroll
      for (int ni = 0; ni < 4; ++ni)
        b[ni] = *(const bf16x8*)&Bsm[(wc * 64 + ni * 16 + lr) * 64 + xk];
#pragma unroll
      for (int mi = 0; mi < 4; ++mi)
#pragma unroll
        for (int ni = 0; ni < 4; ++ni)
          acc[mi][ni] = __builtin_amdgcn_mfma_f32_16x16x32_bf16(a[mi], b[ni], acc[mi][ni], 0, 0, 0);
    }
    __syncthreads();
  }

  float en[4]; int kb[4];
#pragma unroll
  for (int ni = 0; ni < 4; ++ni) {
    kb[ni] = n0 + wc * 64 + ni * 16 + lr;
    en[ni] = enorms[kb[ni]];
  }
  const int p = n * 2 + wc;
#pragma unroll
  for (int mi = 0; mi < 4; ++mi)
#pragma unroll
    for (int j = 0; j < 4; ++j) {
      float bv = fmaf(-2.f, acc[mi][0][j], en[0]);
      int bk = kb[0];
      float sv = FLT_MAX;
#pragma unroll
      for (int ni = 1; ni < 4; ++ni) {
        const float v = fmaf(-2.f, acc[mi][ni][j], en[ni]);
        if (v < bv) { sv = bv; bv = v; bk = kb[ni]; }
        else sv = fminf(sv, v);
      }
#pragma unroll
      for (int msk = 1; msk < 16; msk <<= 1) {
        const float ob = __shfl_xor(bv, msk);
        const int   ok = __shfl_xor(bk, msk);
        const float os = __shfl_xor(sv, msk);
        if (ob < bv || (ob == bv && ok < bk)) { sv = fminf(bv, os); bv = ob; bk = ok; }
        else sv = fminf(sv, ob);
      }
      if (lr == 0) {
        const int row = m0 + wr * 64 + mi * 16 + lg * 4 + j;
        pval[(size_t)p * mrows + row] = bv;
        psec[(size_t)p * mrows + row] = sv;
        pidx[(size_t)p * mrows + row] = bk;
      }
    }
}

// merge 32 panel partials -> provisional best; flag ambiguous rows (eps1)
__global__ __launch_bounds__(256) void kreduce(const float* __restrict__ pval,
    const float* __restrict__ psec, const int* __restrict__ pidx,
    int* __restrict__ idx, int* __restrict__ nflag, int* __restrict__ flags) {
  const int r = blockIdx.x * 256 + threadIdx.x;
  float bv = FLT_MAX, sv = FLT_MAX;
  int bk = 0;
#pragma unroll
  for (int p = 0; p < 32; ++p) {
    const float v1 = pval[p * NROWS + r];
    const int   k1 = pidx[p * NROWS + r];
    const float s1 = psec[p * NROWS + r];
    if (v1 < bv || (v1 == bv && k1 < bk)) { sv = fminf(bv, s1); bv = v1; bk = k1; }
    else sv = fminf(sv, v1);
  }
  idx[r] = bk;
  if (sv - bv < EPS1) {
    const int pos = atomicAdd(nflag, 1);
    if (pos < CAP1) flags[pos] = r;
  }
}

// gather flagged rows' split-h into dense Ag [CAP1][1024]
__global__ __launch_bounds__(256) void kgather(const unsigned short* __restrict__ Ap,
    const int* __restrict__ flags, const int* __restrict__ nflag,
    unsigned short* __restrict__ Ag) {
  const int nf = min(*nflag, CAP1);
  const int t = threadIdx.x;
  const int g8 = blockIdx.x;            // 2048 blocks x 8 rows = CAP1
  for (int i = t; i < 8 * 256; i += 256) {
    const int rr = i >> 8;
    const int g = g8 * 8 + rr;
    if (g < nf) {
      const int c = i & 255;
      ((ushort4*)(Ag + (size_t)g * 1024))[c] =
          ((const ushort4*)(Ap + (size_t)flags[g] * 1024))[c];
    }
  }
}

// merge stage-2 partials: confident rows -> final idx; near-ties -> stage-3
__global__ __launch_bounds__(256) void kreduce2(const float* __restrict__ pval2,
    const float* __restrict__ psec2, const int* __restrict__ pidx2,
    const int* __restrict__ flags, const int* __restrict__ nflag,
    int* __restrict__ idx, int* __restrict__ nflag2, int* __restrict__ flags2) {
  const int nf = min(*nflag, CAP1);
  const int g = blockIdx.x * 256 + threadIdx.x;   // grid 64 -> CAP1 threads
  if (g >= nf) return;
  float bv = FLT_MAX, sv = FLT_MAX;
  int bk = 0;
#pragma unroll
  for (int p = 0; p < 32; ++p) {
    const float v1 = pval2[p * CAP1 + g];
    const int   k1 = pidx2[p * CAP1 + g];
    const float s1 = psec2[p * CAP1 + g];
    if (v1 < bv || (v1 == bv && k1 < bk)) { sv = fminf(bv, s1); bv = v1; bk = k1; }
    else sv = fminf(sv, v1);
  }
  const int r = flags[g];
  if (sv - bv >= EPS2) {
    idx[r] = bk;
  } else {
    const int pos = atomicAdd(nflag2, 1);
    if (pos < CAP2) flags2[pos] = r;
  }
}

// fp32 rescore, one block per flagged row (wide & shallow, r6-proven)
__global__ __launch_bounds__(256) void krescore(const float* __restrict__ h,
    const float* __restrict__ emb, const float* __restrict__ enorms,
    const int* __restrict__ flags, const int* __restrict__ nflag,
    int* __restrict__ idx) {
  __shared__ float hr[512];
  __shared__ float rv[256];
  __shared__ int   rk[256];
  const int t = threadIdx.x;
  const int nf = min(*nflag, CAP2);
  for (int f = blockIdx.x; f < nf; f += gridDim.x) {
    __syncthreads();
    const int r = flags[f];
    if (t < 128) ((float4*)hr)[t] = ((const float4*)(h + (size_t)r * 512))[t];
    __syncthreads();
    float bv = FLT_MAX; int bk = 0;
#pragma unroll
    for (int j = 0; j < 8; ++j) {
      const int c = t + j * 256;
      const float* er = emb + (size_t)c * 512;
      float d0 = 0.f, d1 = 0.f, d2 = 0.f, d3 = 0.f;
#pragma unroll 4
      for (int d = 0; d < 512; d += 16) {
        const float4 e0 = *(const float4*)&er[d];
        const float4 e1 = *(const float4*)&er[d + 4];
        const float4 e2 = *(const float4*)&er[d + 8];
        const float4 e3 = *(const float4*)&er[d + 12];
        d0 = fmaf(hr[d+0],  e0.x, d0); d0 = fmaf(hr[d+1],  e0.y, d0);
        d0 = fmaf(hr[d+2],  e0.z, d0); d0 = fmaf(hr[d+3],  e0.w, d0);
        d1 = fmaf(hr[d+4],  e1.x, d1); d1 = fmaf(hr[d+5],  e1.y, d1);
        d1 = fmaf(hr[d+6],  e1.z, d1); d1 = fmaf(hr[d+7],  e1.w, d1);
        d2 = fmaf(hr[d+8],  e2.x, d2); d2 = fmaf(hr[d+9],  e2.y, d2);
        d2 = fmaf(hr[d+10], e2.z, d2); d2 = fmaf(hr[d+11], e2.w, d2);
        d3 = fmaf(hr[d+12], e3.x, d3); d3 = fmaf(hr[d+13], e3.y, d3);
        d3 = fmaf(hr[d+14], e3.z, d3); d3 = fmaf(hr[d+15], e3.w, d3);
      }
      const float dot = (d0 + d1) + (d2 + d3);
      const float v = fmaf(-2.f, dot, enorms[c]);
      if (v < bv) { bv = v; bk = c; }
    }
    rv[t] = bv; rk[t] = bk;
    __syncthreads();
    for (int off = 128; off > 0; off >>= 1) {
      if (t < off) {
        const float v2 = rv[t + off];
        const int   k2 = rk[t + off];
        if (v2 < rv[t] || (v2 == rv[t] && k2 < rk[t])) { rv[t] = v2; rk[t] = k2; }
      }
      __syncthreads();
    }
    if (t == 0) idx[r] = rk[0];
  }
}

__global__ __launch_bounds__(256) void kquant(const float* __restrict__ h,
    const float* __restrict__ emb, const int* __restrict__ idx,
    float* __restrict__ qout, double* __restrict__ loss_accum) {
  const int tid = blockIdx.x * 256 + threadIdx.x;
  float ls = 0.f;
#pragma unroll
  for (int i = 0; i < 4; ++i) {
    const int f = tid + i * 4194304;
    const int n = f >> 9;
    const int c = f & 511;
    const float hv = h[f];
    const float ev = emb[(size_t)idx[n] * DDIM + c];
    qout[f] = hv + (ev - hv);
    const float d = ev - hv;
    ls = fmaf(d, d, ls);
  }
  double s = (double)ls;
#pragma unroll
  for (int off = 32; off > 0; off >>= 1) s += __shfl_down(s, off);
  __shared__ double sred[4];
  if ((threadIdx.x & 63) == 0) sred[threadIdx.x >> 6] = s;
  __syncthreads();
  if (threadIdx.x == 0)
    atomicAdd(loss_accum, sred[0] + sred[1] + sred[2] + sred[3]);
}

__global__ __launch_bounds__(256) void khist(const int* __restrict__ idx,
                                             int* __restrict__ counts) {
  const int n = blockIdx.x * 256 + threadIdx.x;
  atomicAdd(&counts[idx[n]], 1);
}

__global__ __launch_bounds__(256) void kenc(const int* __restrict__ idx,
                                            float2* __restrict__ out2) {
  const int nt = 2048 * 256;
  for (int f2 = blockIdx.x * 256 + threadIdx.x; f2 < 33554432; f2 += nt) {
    const int n  = f2 >> 10;
    const int k  = (f2 & 1023) << 1;
    const int in = idx[n];
    out2[f2] = make_float2(in == k ? 1.f : 0.f, in == (k + 1) ? 1.f : 0.f);
  }
}

__global__ __launch_bounds__(256) void kfinal(const double* __restrict__ loss_accum,
    const int* __restrict__ counts, float* __restrict__ out) {
  __shared__ double sred[256];
  const int t = threadIdx.x;
  double s = 0.0;
  for (int k = t; k < KCODES; k += 256) {
    const double p = counts[k] / 32768.0;
    s += p * log(p + 1e-10);
  }
  sred[t] = s;
  __syncthreads();
  for (int off = 128; off > 0; off >>= 1) {
    if (t < off) sred[t] += sred[t + off];
    __syncthreads();
  }
  if (t == 0) {
    out[0]        = (float)(0.25 * loss_accum[0] / (32768.0 * 512.0));
    out[OUT_PERP] = (float)exp(-sred[0]);
  }
}

extern "C" void kernel_launch(void* const* d_in, const int* in_sizes, int n_in,
                              void* d_out, int out_size, void* d_ws, size_t ws_size,
                              hipStream_t stream) {
  const float* x0  = (const float*)d_in[0];
  const float* x1  = (const float*)d_in[1];
  const float* W   = (const float*)d_in[2];
  const float* b   = (const float*)d_in[3];
  const float* emb = (const float*)d_in[4];
  float* out = (float*)d_out;
  float* S   = out + OUT_ENC + 2;

  unsigned short* Ap = (unsigned short*)(S + AP_OFF);
  unsigned short* Bp = (unsigned short*)(S + BP_OFF);
  unsigned short* Xs = (unsigned short*)(S + XS_OFF);
  unsigned short* Ws = (unsigned short*)(S + WS_OFF);
  unsigned short* Ag = (unsigned short*)(S + AG_OFF);
  int* pidx  = (int*)(S + PIDX_OFF);
  int* pidx2 = (int*)(S + PIDX2_OFF);

  double* loss_accum = (double*)d_ws;
  int* nflag  = (int*)((char*)d_ws + 8);
  int* nflag2 = (int*)((char*)d_ws + 12);
  int* counts = (int*)((char*)d_ws + 16);
  int* idx    = (int*)((char*)d_ws + 8208);
  int* flags  = (int*)((char*)d_ws + 139280);   // CAP1 ints
  int* flags2 = (int*)((char*)d_ws + 204816);   // CAP2 ints

  hipMemsetAsync(d_ws, 0, 8208, stream);

  ksplit_half<<<8192, 256, 0, stream>>>(x0, Xs, 0);
  ksplit_half<<<8192, 256, 0, stream>>>(x1, Xs, 256);
  ksplit_full<<<256,  256, 0, stream>>>(W, Ws);
  ksplit_full<<<1024, 256, 0, stream>>>(emb, Bp);
  kenorm<<<2048, 64, 0, stream>>>(emb, S + ENORM_OFF);
  kgemm1_mfma<<<1024, 256, 0, stream>>>(Xs, Ws, b, S + H_OFF, Ap);
  kdist_t<16, false><<<4096, 256, 0, stream>>>(Ap, Bp, S + ENORM_OFF,
      S + PVAL_OFF, S + PSEC_OFF, pidx, nflag, NROWS);
  kreduce<<<128, 256, 0, stream>>>(S + PVAL_OFF, S + PSEC_OFF, pidx, idx, nflag, flags);
  kgather<<<2048, 256, 0, stream>>>(Ap, flags, nflag, Ag);
  kdist_t<24, true><<<2048, 256, 0, stream>>>(Ag, Bp, S + ENORM_OFF,
      S + PVAL2_OFF, S + PSEC2_OFF, pidx2, nflag, CAP1);
  kreduce2<<<64, 256, 0, stream>>>(S + PVAL2_OFF, S + PSEC2_OFF, pidx2,
                                   flags, nflag, idx, nflag2, flags2);
  krescore<<<256, 256, 0, stream>>>(S + H_OFF, emb, S + ENORM_OFF,
                                    flags2, nflag2, idx);
  kquant<<<16384, 256, 0, stream>>>(S + H_OFF, emb, idx, out + OUT_Q, loss_accum);
  khist<<<128, 256, 0, stream>>>(idx, counts);
  kenc<<<2048, 256, 0, stream>>>(idx, (float2*)(out + OUT_ENC));
  kfinal<<<1, 256, 0, stream>>>(loss_accum, counts, out);
}